// Round 1
// baseline (135.059 us; speedup 1.0000x reference)
//
#include <hip/hip_runtime.h>

#define YGRID 7
#define COORD 5.0f
#define NO_OBJ 0.5f
#define NCELLS (8192 * 49)
#define INV_B (1.0f / 8192.0f)

__device__ __forceinline__ float iou_calc(float ax1, float ay1, float ax2, float ay2,
                                          float bx1, float by1, float bx2, float by2) {
    float iw = fminf(ax2, bx2) - fmaxf(ax1, bx1);
    iw = fmaxf(iw, 0.0f);
    float ih = fminf(ay2, by2) - fmaxf(ay1, by1);
    ih = fmaxf(ih, 0.0f);
    float inter = iw * ih;
    float area_a = (ax2 - ax1) * (ay2 - ay1);
    float area_b = (bx2 - bx1) * (by2 - by1);
    float uni = area_a + area_b - inter;
    return uni > 0.0f ? inter / uni : 0.0f;
}

__global__ __launch_bounds__(256) void yolo_loss_kernel(
    const float* __restrict__ data, const float* __restrict__ labels,
    float* __restrict__ out) {
    int idx = blockIdx.x * blockDim.x + threadIdx.x;

    float acc = 0.0f;
    if (idx < NCELLS) {
        int cell = idx % 49;
        float r = (float)(cell / 7);
        float c = (float)(cell % 7);

        // 30 floats per cell = 120 bytes, 8B-aligned -> float2 loads are safe.
        const float2* dp = (const float2*)(data + (size_t)idx * 30);
        const float2* lp = (const float2*)(labels + (size_t)idx * 30);
        float d[30], l[30];
#pragma unroll
        for (int i = 0; i < 15; i++) {
            float2 v = dp[i];
            d[2 * i] = v.x; d[2 * i + 1] = v.y;
        }
#pragma unroll
        for (int i = 0; i < 15; i++) {
            float2 v = lp[i];
            l[2 * i] = v.x; l[2 * i + 1] = v.y;
        }

        const float inv_g = 1.0f / (float)YGRID;
        // box1 corners
        float cx1 = (d[0] + c) * inv_g, cy1 = (d[1] + r) * inv_g;
        float b1x1 = cx1 - d[2] * 0.5f, b1y1 = cy1 - d[3] * 0.5f;
        float b1x2 = cx1 + d[2] * 0.5f, b1y2 = cy1 + d[3] * 0.5f;
        // box2 corners
        float cx2 = (d[5] + c) * inv_g, cy2 = (d[6] + r) * inv_g;
        float b2x1 = cx2 - d[7] * 0.5f, b2y1 = cy2 - d[8] * 0.5f;
        float b2x2 = cx2 + d[7] * 0.5f, b2y2 = cy2 + d[8] * 0.5f;
        // gt corners
        float gx = (l[0] + c) * inv_g, gy = (l[1] + r) * inv_g;
        float gx1 = gx - l[2] * 0.5f, gy1 = gy - l[3] * 0.5f;
        float gx2 = gx + l[2] * 0.5f, gy2 = gy + l[3] * 0.5f;

        float iou1 = iou_calc(b1x1, b1y1, b1x2, b1y2, gx1, gy1, gx2, gy2);
        float iou2 = iou_calc(b2x1, b2y1, b2x2, b2y2, gx1, gy1, gx2, gy2);
        bool resp1 = iou1 >= iou2;

        float xy1 = (d[0] - l[0]) * (d[0] - l[0]) + (d[1] - l[1]) * (d[1] - l[1]);
        float xy2 = (d[5] - l[5]) * (d[5] - l[5]) + (d[6] - l[6]) * (d[6] - l[6]);
        float s2 = sqrtf(d[2]) - sqrtf(l[2]);
        float s3 = sqrtf(d[3]) - sqrtf(l[3]);
        float wh1 = s2 * s2 + s3 * s3;
        float s7 = sqrtf(d[7]) - sqrtf(l[7]);
        float s8 = sqrtf(d[8]) - sqrtf(l[8]);
        float wh2 = s7 * s7 + s8 * s8;

        float d4 = d[4], d9 = d[9];
        float co = COORD * (resp1 ? xy1 : xy2);
        float wh = COORD * (resp1 ? wh1 : wh2);
        float ci = resp1 ? (d4 - iou1) * (d4 - iou1) : (d9 - iou2) * (d9 - iou2);
        float noobj_in = NO_OBJ * (resp1 ? d9 * d9 : d4 * d4);
        float cls = 0.0f;
#pragma unroll
        for (int i = 10; i < 30; i++) {
            float t = d[i] - l[i];
            cls += t * t;
        }

        float loss = (l[4] == 1.0f)
                         ? (co + wh + ci + noobj_in + cls)
                         : NO_OBJ * (d4 * d4 + d9 * d9);
        acc = loss * INV_B;
    }

    // wave (64-lane) reduction
#pragma unroll
    for (int off = 32; off > 0; off >>= 1)
        acc += __shfl_down(acc, off, 64);

    __shared__ float wsum[4];
    int lane = threadIdx.x & 63;
    int wid = threadIdx.x >> 6;
    if (lane == 0) wsum[wid] = acc;
    __syncthreads();
    if (threadIdx.x == 0) {
        float t = wsum[0] + wsum[1] + wsum[2] + wsum[3];
        atomicAdd(out, t);
    }
}

extern "C" void kernel_launch(void* const* d_in, const int* in_sizes, int n_in,
                              void* d_out, int out_size, void* d_ws, size_t ws_size,
                              hipStream_t stream) {
    const float* data = (const float*)d_in[0];
    const float* labels = (const float*)d_in[1];
    float* out = (float*)d_out;

    hipMemsetAsync(out, 0, sizeof(float) * out_size, stream);

    int nblocks = NCELLS / 256;  // 401408 / 256 = 1568, exact
    yolo_loss_kernel<<<nblocks, 256, 0, stream>>>(data, labels, out);
}

// Round 2
// 118.483 us; speedup vs baseline: 1.1399x; 1.1399x over previous
//
#include <hip/hip_runtime.h>

#define YGRID 7
#define COORD 5.0f
#define NO_OBJ 0.5f
#define NCELLS (8192 * 49)
#define INV_B (1.0f / 8192.0f)

#define CPB 256                      // cells per block (= threads per block)
#define FPB (CPB * 30)               // floats per block per array = 7680
#define V4PB (FPB / 4)               // float4 per block per array = 1920

__device__ __forceinline__ float iou_calc(float ax1, float ay1, float ax2, float ay2,
                                          float bx1, float by1, float bx2, float by2) {
    float iw = fminf(ax2, bx2) - fmaxf(ax1, bx1);
    iw = fmaxf(iw, 0.0f);
    float ih = fminf(ay2, by2) - fmaxf(ay1, by1);
    ih = fmaxf(ih, 0.0f);
    float inter = iw * ih;
    float area_a = (ax2 - ax1) * (ay2 - ay1);
    float area_b = (bx2 - bx1) * (by2 - by1);
    float uni = area_a + area_b - inter;
    return uni > 0.0f ? inter / uni : 0.0f;
}

__global__ __launch_bounds__(256) void yolo_loss_kernel(
    const float* __restrict__ data, const float* __restrict__ labels,
    float* __restrict__ out) {
    __shared__ float sd[FPB];
    __shared__ float sl[FPB];

    const int tid = threadIdx.x;
    const size_t base = (size_t)blockIdx.x * FPB;

    // Coalesced staging: block slab is 30720 B, 16B-aligned (30720 % 16 == 0).
    const float4* gd = (const float4*)(data + base);
    const float4* gl = (const float4*)(labels + base);
    float4* sd4 = (float4*)sd;
    float4* sl4 = (float4*)sl;
#pragma unroll
    for (int i = 0; i < 7; i++) {
        sd4[i * 256 + tid] = gd[i * 256 + tid];
        sl4[i * 256 + tid] = gl[i * 256 + tid];
    }
    if (tid < V4PB - 7 * 256) {  // remaining 128 float4s
        sd4[7 * 256 + tid] = gd[7 * 256 + tid];
        sl4[7 * 256 + tid] = gl[7 * 256 + tid];
    }
    __syncthreads();

    // Per-cell gather from LDS (stride-30 -> 4-way bank conflict, cheap).
    const int idx = blockIdx.x * CPB + tid;
    const int cell = idx % 49;
    const float r = (float)(cell / 7);
    const float c = (float)(cell % 7);

    float d[30], l[30];
    const float2* dp = (const float2*)(sd + tid * 30);
    const float2* lp = (const float2*)(sl + tid * 30);
#pragma unroll
    for (int i = 0; i < 15; i++) {
        float2 v = dp[i];
        d[2 * i] = v.x; d[2 * i + 1] = v.y;
        float2 w = lp[i];
        l[2 * i] = w.x; l[2 * i + 1] = w.y;
    }

    const float inv_g = 1.0f / (float)YGRID;
    float cx1 = (d[0] + c) * inv_g, cy1 = (d[1] + r) * inv_g;
    float b1x1 = cx1 - d[2] * 0.5f, b1y1 = cy1 - d[3] * 0.5f;
    float b1x2 = cx1 + d[2] * 0.5f, b1y2 = cy1 + d[3] * 0.5f;
    float cx2 = (d[5] + c) * inv_g, cy2 = (d[6] + r) * inv_g;
    float b2x1 = cx2 - d[7] * 0.5f, b2y1 = cy2 - d[8] * 0.5f;
    float b2x2 = cx2 + d[7] * 0.5f, b2y2 = cy2 + d[8] * 0.5f;
    float gx = (l[0] + c) * inv_g, gy = (l[1] + r) * inv_g;
    float gx1 = gx - l[2] * 0.5f, gy1 = gy - l[3] * 0.5f;
    float gx2 = gx + l[2] * 0.5f, gy2 = gy + l[3] * 0.5f;

    float iou1 = iou_calc(b1x1, b1y1, b1x2, b1y2, gx1, gy1, gx2, gy2);
    float iou2 = iou_calc(b2x1, b2y1, b2x2, b2y2, gx1, gy1, gx2, gy2);
    bool resp1 = iou1 >= iou2;

    float xy1 = (d[0] - l[0]) * (d[0] - l[0]) + (d[1] - l[1]) * (d[1] - l[1]);
    float xy2 = (d[5] - l[5]) * (d[5] - l[5]) + (d[6] - l[6]) * (d[6] - l[6]);
    float s2 = sqrtf(d[2]) - sqrtf(l[2]);
    float s3 = sqrtf(d[3]) - sqrtf(l[3]);
    float wh1 = s2 * s2 + s3 * s3;
    float s7 = sqrtf(d[7]) - sqrtf(l[7]);
    float s8 = sqrtf(d[8]) - sqrtf(l[8]);
    float wh2 = s7 * s7 + s8 * s8;

    float d4 = d[4], d9 = d[9];
    float co = COORD * (resp1 ? xy1 : xy2);
    float wh = COORD * (resp1 ? wh1 : wh2);
    float ci = resp1 ? (d4 - iou1) * (d4 - iou1) : (d9 - iou2) * (d9 - iou2);
    float noobj_in = NO_OBJ * (resp1 ? d9 * d9 : d4 * d4);
    float cls = 0.0f;
#pragma unroll
    for (int i = 10; i < 30; i++) {
        float t = d[i] - l[i];
        cls += t * t;
    }

    float loss = (l[4] == 1.0f)
                     ? (co + wh + ci + noobj_in + cls)
                     : NO_OBJ * (d4 * d4 + d9 * d9);
    float acc = loss * INV_B;

    // wave (64-lane) reduction
#pragma unroll
    for (int off = 32; off > 0; off >>= 1)
        acc += __shfl_down(acc, off, 64);

    __shared__ float wsum[4];
    int lane = tid & 63;
    int wid = tid >> 6;
    if (lane == 0) wsum[wid] = acc;
    __syncthreads();
    if (tid == 0) {
        float t = wsum[0] + wsum[1] + wsum[2] + wsum[3];
        atomicAdd(out, t);
    }
}

extern "C" void kernel_launch(void* const* d_in, const int* in_sizes, int n_in,
                              void* d_out, int out_size, void* d_ws, size_t ws_size,
                              hipStream_t stream) {
    const float* data = (const float*)d_in[0];
    const float* labels = (const float*)d_in[1];
    float* out = (float*)d_out;

    hipMemsetAsync(out, 0, sizeof(float) * out_size, stream);

    int nblocks = NCELLS / CPB;  // 401408 / 256 = 1568, exact
    yolo_loss_kernel<<<nblocks, CPB, 0, stream>>>(data, labels, out);
}